// Round 10
// baseline (739.468 us; speedup 1.0000x reference)
//
#include <hip/hip_runtime.h>

#define D 128

// ---------------- MFMA frag types (per guide: short8 holds 8 bf16) --------
typedef __attribute__((ext_vector_type(8))) short bf16x8;
typedef __attribute__((ext_vector_type(4))) float f32x4;

union Frag {
    unsigned short s[8];
    uint4 u;
    bf16x8 v;
};

__device__ inline unsigned short bf16_rne(float x) {
    unsigned u = __float_as_uint(x);
    return (unsigned short)((u + 0x7fffu + ((u >> 16) & 1)) >> 16);
}

// ---------------- edge dtype handling ----------------
// Reference declares int64 edge_index, but JAX default (x64 disabled) yields
// int32. Detect on device: if the first 4096 odd 32-bit words are all zero,
// the buffer is little-endian int64 (values < 2^17).
__global__ void detect64_k(const int* __restrict__ raw, int* __restrict__ flag) {
    __shared__ int bad;
    if (threadIdx.x == 0) bad = 0;
    __syncthreads();
    for (int i = threadIdx.x; i < 4096; i += 256)
        if (raw[2 * i + 1] != 0) bad = 1;   // benign race, all write 1
    __syncthreads();
    if (threadIdx.x == 0) *flag = bad ? 0 : 1;
}

// ---------------- degree ----------------
// unroll-4 grid-stride: 4 independent loads + 4 fire-and-forget atomics
__global__ void hist_k(const int* __restrict__ raw, const int* __restrict__ flag,
                       int* __restrict__ cnt, int E) {
    bool is64 = (*flag != 0);
    int S = gridDim.x * blockDim.x;
    int i = blockIdx.x * blockDim.x + threadIdx.x;
    for (; i + 3 * S < E; i += 4 * S) {
        int d0 = is64 ? raw[2 * (E + i)]         : raw[E + i];
        int d1 = is64 ? raw[2 * (E + i + S)]     : raw[E + i + S];
        int d2 = is64 ? raw[2 * (E + i + 2 * S)] : raw[E + i + 2 * S];
        int d3 = is64 ? raw[2 * (E + i + 3 * S)] : raw[E + i + 3 * S];
        atomicAdd(&cnt[d0], 1);
        atomicAdd(&cnt[d1], 1);
        atomicAdd(&cnt[d2], 1);
        atomicAdd(&cnt[d3], 1);
    }
    for (; i < E; i += S) {
        int d = is64 ? raw[2 * (E + i)] : raw[E + i];
        atomicAdd(&cnt[d], 1);
    }
}

__global__ void dinv_k(const int* __restrict__ cnt, float* __restrict__ dinv, int n) {
    int i = blockIdx.x * blockDim.x + threadIdx.x;
    if (i < n) dinv[i] = rsqrtf((float)cnt[i] + 1.0f);   // +1 = self-loop
}

// ---------------- CSR build: block scan (1024 elems/block) ----------------
__global__ void scan1_k(const int* __restrict__ cnt, int* __restrict__ rp,
                        int* __restrict__ part, int n) {
    __shared__ int s[256];
    int t = threadIdx.x;
    int base = blockIdx.x * 1024 + t * 4;
    int v0 = 0, v1 = 0, v2 = 0, v3 = 0;
    if (base + 0 < n) v0 = cnt[base + 0];
    if (base + 1 < n) v1 = cnt[base + 1];
    if (base + 2 < n) v2 = cnt[base + 2];
    if (base + 3 < n) v3 = cnt[base + 3];
    int sum = v0 + v1 + v2 + v3;
    s[t] = sum;
    __syncthreads();
    for (int off = 1; off < 256; off <<= 1) {
        int xv = 0;
        if (t >= off) xv = s[t - off];
        __syncthreads();
        s[t] += xv;
        __syncthreads();
    }
    int run = s[t] - sum;   // exclusive prefix for this thread's 4 elems
    if (base + 0 < n) rp[base + 0] = run; run += v0;
    if (base + 1 < n) rp[base + 1] = run; run += v1;
    if (base + 2 < n) rp[base + 2] = run; run += v2;
    if (base + 3 < n) rp[base + 3] = run;
    if (t == 255) part[blockIdx.x] = s[255];
}

// parallel 1-block exclusive scan of the partials (nb <= 256 fast path)
__global__ void scan2_k(int* __restrict__ part, int nb) {
    if (nb <= 256) {
        __shared__ int s[256];
        int t = threadIdx.x;
        int v = (t < nb) ? part[t] : 0;
        s[t] = v;
        __syncthreads();
        for (int off = 1; off < 256; off <<= 1) {
            int xv = 0;
            if (t >= off) xv = s[t - off];
            __syncthreads();
            s[t] += xv;
            __syncthreads();
        }
        if (t < nb) part[t] = s[t] - v;   // exclusive
    } else if (threadIdx.x == 0) {
        int run = 0;
        for (int i = 0; i < nb; i++) { int v = part[i]; part[i] = run; run += v; }
    }
}

__global__ void scan3_k(int* __restrict__ rp, int* __restrict__ cursor,
                        const int* __restrict__ part, int n, int E) {
    int i = blockIdx.x * blockDim.x + threadIdx.x;
    if (i < n) {
        int v = rp[i] + part[i >> 10];
        rp[i] = v;
        cursor[i] = v;
    }
    if (i == 0) rp[n] = E;
}

// CSR entry = {src index, norm weight dinv[src]*dinv[dst]} packed as int2.
// unroll-4 grid-stride: 4 independent atomicAdd round-trips in flight per
// thread (the atomic->store dependence chain was the R7 bottleneck:
// VALUBusy 0.6%, hbm 11%, 120us).
__global__ void build_k(const int* __restrict__ raw, const int* __restrict__ flag,
                        const float* __restrict__ dinv,
                        int* __restrict__ cursor, int2* __restrict__ csr, int E) {
    bool is64 = (*flag != 0);
    int S = gridDim.x * blockDim.x;
    int i = blockIdx.x * blockDim.x + threadIdx.x;
    for (; i + 3 * S < E; i += 4 * S) {
        int i0 = i, i1 = i + S, i2 = i + 2 * S, i3 = i + 3 * S;
        int s0 = is64 ? raw[2 * i0] : raw[i0];
        int s1 = is64 ? raw[2 * i1] : raw[i1];
        int s2 = is64 ? raw[2 * i2] : raw[i2];
        int s3 = is64 ? raw[2 * i3] : raw[i3];
        int d0 = is64 ? raw[2 * (E + i0)] : raw[E + i0];
        int d1 = is64 ? raw[2 * (E + i1)] : raw[E + i1];
        int d2 = is64 ? raw[2 * (E + i2)] : raw[E + i2];
        int d3 = is64 ? raw[2 * (E + i3)] : raw[E + i3];
        // 4 independent atomic round-trips in flight
        int p0 = atomicAdd(&cursor[d0], 1);
        int p1 = atomicAdd(&cursor[d1], 1);
        int p2 = atomicAdd(&cursor[d2], 1);
        int p3 = atomicAdd(&cursor[d3], 1);
        float w0 = dinv[s0] * dinv[d0];
        float w1 = dinv[s1] * dinv[d1];
        float w2 = dinv[s2] * dinv[d2];
        float w3 = dinv[s3] * dinv[d3];
        csr[p0] = make_int2(s0, __float_as_int(w0));
        csr[p1] = make_int2(s1, __float_as_int(w1));
        csr[p2] = make_int2(s2, __float_as_int(w2));
        csr[p3] = make_int2(s3, __float_as_int(w3));
    }
    for (; i < E; i += S) {
        int s = is64 ? raw[2 * i] : raw[i];
        int d = is64 ? raw[2 * (E + i)] : raw[E + i];
        int pos = atomicAdd(&cursor[d], 1);
        float w = dinv[s] * dinv[d];
        csr[pos] = make_int2(s, __float_as_int(w));
    }
}

// ---------------- W pre-split + frag-pack (once per call, per layer) -------
__global__ void pack_k(const float* __restrict__ W, uint4* __restrict__ whi,
                       uint4* __restrict__ wlo) {
    int id = blockIdx.x * 256 + threadIdx.x;   // 2048 frag-lanes
    if (id >= 2048) return;
    int lane = id & 63, st = id >> 6;          // st = s*8 + t
    int s = st >> 3, t = st & 7;
    int col = t * 16 + (lane & 15);
    int kb = s * 32 + ((lane >> 4) & 3) * 8;
    Frag H, L;
#pragma unroll
    for (int j = 0; j < 8; ++j) {
        float x = W[(size_t)(kb + j) * D + col];
        unsigned u = __float_as_uint(x);
        unsigned r = (u + 0x7fffu + ((u >> 16) & 1)) & 0xffff0000u;
        H.s[j] = (unsigned short)(r >> 16);
        L.s[j] = bf16_rne(x - __uint_as_float(r));
    }
    whi[st * 64 + lane] = H.u;
    wlo[st * 64 + lane] = L.u;
}

// ---------------- GEMM: H = preop(A) @ W via split-bf16 MFMA ---------------
// f32 = bf16_hi + bf16_lo; D = Ah*Wh + Al*Wh + Ah*Wl (dropped Al*Wl <= 2^-18).
template <int PRE>   // 0: identity, 1: relu on A-load
__global__ __launch_bounds__(256) void gemm_mfma_k(const float* __restrict__ A,
        const uint4* __restrict__ whi, const uint4* __restrict__ wlo,
        float* __restrict__ H, int M) {
    int wv = threadIdx.x >> 6, lane = threadIdx.x & 63;
    int row0 = blockIdx.x * 64 + wv * 16;
    int arow = row0 + (lane & 15);
    if (arow >= M) arow = M - 1;                       // clamp; stores guarded
    const float* ap = A + (size_t)arow * D + ((lane >> 4) & 3) * 8;
    f32x4 acc[8];
#pragma unroll
    for (int t = 0; t < 8; ++t) acc[t] = (f32x4){0.f, 0.f, 0.f, 0.f};
#pragma unroll
    for (int s = 0; s < 4; ++s) {
        float4 a0 = *(const float4*)(ap + s * 32);
        float4 a1 = *(const float4*)(ap + s * 32 + 4);
        float av[8] = {a0.x, a0.y, a0.z, a0.w, a1.x, a1.y, a1.z, a1.w};
        Frag Ah, Al;
#pragma unroll
        for (int j = 0; j < 8; ++j) {
            float x = av[j];
            if (PRE) x = fmaxf(x, 0.f);
            unsigned u = __float_as_uint(x);
            unsigned r = (u + 0x7fffu + ((u >> 16) & 1)) & 0xffff0000u;
            Ah.s[j] = (unsigned short)(r >> 16);
            Al.s[j] = bf16_rne(x - __uint_as_float(r));
        }
        const uint4* wh = whi + (size_t)s * 8 * 64 + lane;
        const uint4* wl = wlo + (size_t)s * 8 * 64 + lane;
#pragma unroll
        for (int t = 0; t < 8; ++t) {
            Frag Bh, Bl;
            Bh.u = wh[t * 64];
            Bl.u = wl[t * 64];
            acc[t] = __builtin_amdgcn_mfma_f32_16x16x32_bf16(Ah.v, Bh.v, acc[t], 0, 0, 0);
            acc[t] = __builtin_amdgcn_mfma_f32_16x16x32_bf16(Al.v, Bh.v, acc[t], 0, 0, 0);
            acc[t] = __builtin_amdgcn_mfma_f32_16x16x32_bf16(Ah.v, Bl.v, acc[t], 0, 0, 0);
        }
    }
    // C/D layout (m89-verified): col = lane&15, row = (lane>>4)*4 + reg
    int g = (lane >> 4) & 3, c = lane & 15;
#pragma unroll
    for (int r = 0; r < 4; ++r) {
        int row = row0 + g * 4 + r;
        if (row < M) {
#pragma unroll
            for (int t = 0; t < 8; ++t)
                H[(size_t)row * D + t * 16 + c] = acc[t][r];
        }
    }
}

// ---------------- CSR aggregation: out[n] = b + dinv[n]^2 h[n] + sum --------
// one wave per node; 64 lanes x float2 = 128 cols; 8-edge unroll, weights
// pre-folded in csr. (R7->R9 A/B: 4->8 unroll was null; limiter is the
// random-64B L2-miss path at ~3.9 TB/s, likely near random-access ceiling.)
__global__ __launch_bounds__(256) void agg_k(const float* __restrict__ h,
                                             const float* __restrict__ dinv,
                                             const int* __restrict__ rp,
                                             const int2* __restrict__ csr,
                                             const float* __restrict__ bias,
                                             float* __restrict__ out, int n) {
    int node = (blockIdx.x << 2) + (threadIdx.x >> 6);
    int lane = threadIdx.x & 63;
    if (node >= n) return;
    const float2* h2 = (const float2*)h;
    float2 b2 = ((const float2*)bias)[lane];
    float dn = dinv[node];
    float2 hv = h2[(size_t)node * 64 + lane];
    float sl = dn * dn;   // self-loop norm
    float accx = b2.x + sl * hv.x;
    float accy = b2.y + sl * hv.y;
    int e = rp[node], e1 = rp[node + 1];
    for (; e + 8 <= e1; e += 8) {
        int2 p0 = csr[e + 0], p1 = csr[e + 1], p2 = csr[e + 2], p3 = csr[e + 3];
        int2 p4 = csr[e + 4], p5 = csr[e + 5], p6 = csr[e + 6], p7 = csr[e + 7];
        float2 v0 = h2[(size_t)p0.x * 64 + lane];
        float2 v1 = h2[(size_t)p1.x * 64 + lane];
        float2 v2 = h2[(size_t)p2.x * 64 + lane];
        float2 v3 = h2[(size_t)p3.x * 64 + lane];
        float2 v4 = h2[(size_t)p4.x * 64 + lane];
        float2 v5 = h2[(size_t)p5.x * 64 + lane];
        float2 v6 = h2[(size_t)p6.x * 64 + lane];
        float2 v7 = h2[(size_t)p7.x * 64 + lane];
        float w0 = __int_as_float(p0.y), w1 = __int_as_float(p1.y);
        float w2 = __int_as_float(p2.y), w3 = __int_as_float(p3.y);
        float w4 = __int_as_float(p4.y), w5 = __int_as_float(p5.y);
        float w6 = __int_as_float(p6.y), w7 = __int_as_float(p7.y);
        accx += w0 * v0.x + w1 * v1.x + w2 * v2.x + w3 * v3.x
              + w4 * v4.x + w5 * v5.x + w6 * v6.x + w7 * v7.x;
        accy += w0 * v0.y + w1 * v1.y + w2 * v2.y + w3 * v3.y
              + w4 * v4.y + w5 * v5.y + w6 * v6.y + w7 * v7.y;
    }
    for (; e + 4 <= e1; e += 4) {
        int2 p0 = csr[e + 0], p1 = csr[e + 1], p2 = csr[e + 2], p3 = csr[e + 3];
        float2 v0 = h2[(size_t)p0.x * 64 + lane];
        float2 v1 = h2[(size_t)p1.x * 64 + lane];
        float2 v2 = h2[(size_t)p2.x * 64 + lane];
        float2 v3 = h2[(size_t)p3.x * 64 + lane];
        float w0 = __int_as_float(p0.y), w1 = __int_as_float(p1.y);
        float w2 = __int_as_float(p2.y), w3 = __int_as_float(p3.y);
        accx += w0 * v0.x + w1 * v1.x + w2 * v2.x + w3 * v3.x;
        accy += w0 * v0.y + w1 * v1.y + w2 * v2.y + w3 * v3.y;
    }
    for (; e < e1; ++e) {
        int2 p0 = csr[e];
        float w0 = __int_as_float(p0.y);
        float2 v0 = h2[(size_t)p0.x * 64 + lane];
        accx += w0 * v0.x;
        accy += w0 * v0.y;
    }
    float2 o; o.x = accx; o.y = accy;
    ((float2*)out)[(size_t)node * 64 + lane] = o;
}

extern "C" void kernel_launch(void* const* d_in, const int* in_sizes, int n_in,
                              void* d_out, int out_size, void* d_ws, size_t ws_size,
                              hipStream_t stream) {
    const float* x  = (const float*)d_in[0];
    const int* eraw = (const int*)d_in[1];
    const float* W1 = (const float*)d_in[2];
    const float* b1 = (const float*)d_in[3];
    const float* W2 = (const float*)d_in[4];
    const float* b2 = (const float*)d_in[5];
    const float* W3 = (const float*)d_in[6];
    const float* b3 = (const float*)d_in[7];
    int N = in_sizes[0] / D;
    int E = in_sizes[1] / 2;
    float* out = (float*)d_out;

    // workspace carve-up (~66 MB)
    char* w = (char*)d_ws;
    float* h    = (float*)w; w += (size_t)N * D * 4;
    int2* csr   = (int2*)w;  w += (size_t)E * 8;
    int* cnt    = (int*)w;   w += (size_t)N * 4;
    float* dinv = (float*)w; w += (size_t)N * 4;
    int* rp     = (int*)w;   w += (size_t)(N + 1) * 4;
    int* cursor = (int*)w;   w += (size_t)N * 4;
    int* part   = (int*)w;   w += 1024 * 4;
    int* flag   = (int*)w;   w += 16;
    uint4* whi[3]; uint4* wlo[3];
    for (int l = 0; l < 3; ++l) {
        whi[l] = (uint4*)w; w += 2048 * 16;
        wlo[l] = (uint4*)w; w += 2048 * 16;
    }

    // graph structure (recomputed every call; inputs restored by harness)
    detect64_k<<<1, 256, 0, stream>>>(eraw, flag);
    hipMemsetAsync(cnt, 0, (size_t)N * 4, stream);
    hist_k<<<512, 256, 0, stream>>>(eraw, flag, cnt, E);
    dinv_k<<<(N + 255) / 256, 256, 0, stream>>>(cnt, dinv, N);
    int nb = (N + 1023) / 1024;
    scan1_k<<<nb, 256, 0, stream>>>(cnt, rp, part, N);
    scan2_k<<<1, 256, 0, stream>>>(part, nb);
    scan3_k<<<(N + 255) / 256, 256, 0, stream>>>(rp, cursor, part, N, E);
    build_k<<<512, 256, 0, stream>>>(eraw, flag, dinv, cursor, csr, E);

    // W frag pre-pack (hi/lo split, MFMA lane order)
    pack_k<<<8, 256, 0, stream>>>(W1, whi[0], wlo[0]);
    pack_k<<<8, 256, 0, stream>>>(W2, whi[1], wlo[1]);
    pack_k<<<8, 256, 0, stream>>>(W3, whi[2], wlo[2]);

    int gb = (N + 63) / 64;
    int ab = (N + 3) / 4;
    // layer 1
    gemm_mfma_k<0><<<gb, 256, 0, stream>>>(x, whi[0], wlo[0], h, N);
    agg_k<<<ab, 256, 0, stream>>>(h, dinv, rp, csr, b1, out, N);
    // layer 2 (relu fused into A-load)
    gemm_mfma_k<1><<<gb, 256, 0, stream>>>(out, whi[1], wlo[1], h, N);
    agg_k<<<ab, 256, 0, stream>>>(h, dinv, rp, csr, b2, out, N);
    // layer 3 (no relu after)
    gemm_mfma_k<1><<<gb, 256, 0, stream>>>(out, whi[2], wlo[2], h, N);
    agg_k<<<ab, 256, 0, stream>>>(h, dinv, rp, csr, b3, out, N);
}

// Round 11
// 603.949 us; speedup vs baseline: 1.2244x; 1.2244x over previous
//
#include <hip/hip_runtime.h>

#define D 128

typedef __attribute__((ext_vector_type(8))) short bf16x8;
typedef __attribute__((ext_vector_type(4))) float f32x4;

union Frag {
    unsigned short s[8];
    uint4 u;
    bf16x8 v;
};

__device__ inline unsigned short bf16_rne(float x) {
    unsigned u = __float_as_uint(x);
    return (unsigned short)((u + 0x7fffu + ((u >> 16) & 1)) >> 16);
}

// ---------------- edge dtype handling ----------------
__global__ void detect64_k(const int* __restrict__ raw, int* __restrict__ flag) {
    __shared__ int bad;
    if (threadIdx.x == 0) bad = 0;
    __syncthreads();
    for (int i = threadIdx.x; i < 4096; i += 256)
        if (raw[2 * i + 1] != 0) bad = 1;   // benign race, all write 1
    __syncthreads();
    if (threadIdx.x == 0) *flag = bad ? 0 : 1;
}

// ---------------- degree ----------------
__global__ void hist_k(const int* __restrict__ raw, const int* __restrict__ flag,
                       int* __restrict__ cnt, int E) {
    bool is64 = (*flag != 0);
    int S = gridDim.x * blockDim.x;
    int i = blockIdx.x * blockDim.x + threadIdx.x;
    for (; i + 3 * S < E; i += 4 * S) {
        int d0 = is64 ? raw[2 * (E + i)]         : raw[E + i];
        int d1 = is64 ? raw[2 * (E + i + S)]     : raw[E + i + S];
        int d2 = is64 ? raw[2 * (E + i + 2 * S)] : raw[E + i + 2 * S];
        int d3 = is64 ? raw[2 * (E + i + 3 * S)] : raw[E + i + 3 * S];
        atomicAdd(&cnt[d0], 1);
        atomicAdd(&cnt[d1], 1);
        atomicAdd(&cnt[d2], 1);
        atomicAdd(&cnt[d3], 1);
    }
    for (; i < E; i += S) {
        int d = is64 ? raw[2 * (E + i)] : raw[E + i];
        atomicAdd(&cnt[d], 1);
    }
}

__global__ void dinv_k(const int* __restrict__ cnt, float* __restrict__ dinv, int n) {
    int i = blockIdx.x * blockDim.x + threadIdx.x;
    if (i < n) dinv[i] = rsqrtf((float)cnt[i] + 1.0f);   // +1 = self-loop
}

// ---------------- CSR build: block scan (1024 elems/block) ----------------
__global__ void scan1_k(const int* __restrict__ cnt, int* __restrict__ rp,
                        int* __restrict__ part, int n) {
    __shared__ int s[256];
    int t = threadIdx.x;
    int base = blockIdx.x * 1024 + t * 4;
    int v0 = 0, v1 = 0, v2 = 0, v3 = 0;
    if (base + 0 < n) v0 = cnt[base + 0];
    if (base + 1 < n) v1 = cnt[base + 1];
    if (base + 2 < n) v2 = cnt[base + 2];
    if (base + 3 < n) v3 = cnt[base + 3];
    int sum = v0 + v1 + v2 + v3;
    s[t] = sum;
    __syncthreads();
    for (int off = 1; off < 256; off <<= 1) {
        int xv = 0;
        if (t >= off) xv = s[t - off];
        __syncthreads();
        s[t] += xv;
        __syncthreads();
    }
    int run = s[t] - sum;   // exclusive prefix for this thread's 4 elems
    if (base + 0 < n) rp[base + 0] = run; run += v0;
    if (base + 1 < n) rp[base + 1] = run; run += v1;
    if (base + 2 < n) rp[base + 2] = run; run += v2;
    if (base + 3 < n) rp[base + 3] = run;
    if (t == 255) part[blockIdx.x] = s[255];
}

__global__ void scan2_k(int* __restrict__ part, int nb) {
    if (nb <= 256) {
        __shared__ int s[256];
        int t = threadIdx.x;
        int v = (t < nb) ? part[t] : 0;
        s[t] = v;
        __syncthreads();
        for (int off = 1; off < 256; off <<= 1) {
            int xv = 0;
            if (t >= off) xv = s[t - off];
            __syncthreads();
            s[t] += xv;
            __syncthreads();
        }
        if (t < nb) part[t] = s[t] - v;   // exclusive
    } else if (threadIdx.x == 0) {
        int run = 0;
        for (int i = 0; i < nb; i++) { int v = part[i]; part[i] = run; run += v; }
    }
}

__global__ void scan3_k(int* __restrict__ rp, int* __restrict__ cursor,
                        const int* __restrict__ part, int n, int E) {
    int i = blockIdx.x * blockDim.x + threadIdx.x;
    if (i < n) {
        int v = rp[i] + part[i >> 10];
        rp[i] = v;
        cursor[i] = v;
    }
    if (i == 0) rp[n] = E;
}

// CSR entry = src index only (4 B). Weight dinv[src]*dinv[dst] is recomputed
// in agg (dinv is 400 KB, L2-resident, wave-uniform broadcast). Halves the
// random scatter write traffic that bounds this kernel (R9: WRITE 102 MB at
// 0.94 TB/s ~= the whole 120 us; VALUBusy 0.6%).
__global__ void build_k(const int* __restrict__ raw, const int* __restrict__ flag,
                        int* __restrict__ cursor, int* __restrict__ csr, int E) {
    bool is64 = (*flag != 0);
    int S = gridDim.x * blockDim.x;
    int i = blockIdx.x * blockDim.x + threadIdx.x;
    for (; i + 3 * S < E; i += 4 * S) {
        int i0 = i, i1 = i + S, i2 = i + 2 * S, i3 = i + 3 * S;
        int s0 = is64 ? raw[2 * i0] : raw[i0];
        int s1 = is64 ? raw[2 * i1] : raw[i1];
        int s2 = is64 ? raw[2 * i2] : raw[i2];
        int s3 = is64 ? raw[2 * i3] : raw[i3];
        int d0 = is64 ? raw[2 * (E + i0)] : raw[E + i0];
        int d1 = is64 ? raw[2 * (E + i1)] : raw[E + i1];
        int d2 = is64 ? raw[2 * (E + i2)] : raw[E + i2];
        int d3 = is64 ? raw[2 * (E + i3)] : raw[E + i3];
        int p0 = atomicAdd(&cursor[d0], 1);
        int p1 = atomicAdd(&cursor[d1], 1);
        int p2 = atomicAdd(&cursor[d2], 1);
        int p3 = atomicAdd(&cursor[d3], 1);
        csr[p0] = s0;
        csr[p1] = s1;
        csr[p2] = s2;
        csr[p3] = s3;
    }
    for (; i < E; i += S) {
        int s = is64 ? raw[2 * i] : raw[i];
        int d = is64 ? raw[2 * (E + i)] : raw[E + i];
        int pos = atomicAdd(&cursor[d], 1);
        csr[pos] = s;
    }
}

// ---------------- W pre-split + frag-pack (3 layers in one launch) --------
__global__ void pack_k(const float* __restrict__ W1f, const float* __restrict__ W2f,
                       const float* __restrict__ W3f, uint4* __restrict__ wbuf) {
    int gid = blockIdx.x * 256 + threadIdx.x;   // 3 * 2048 frag-lanes
    int layer = gid >> 11;
    int id = gid & 2047;
    const float* W = layer == 0 ? W1f : (layer == 1 ? W2f : W3f);
    uint4* whi = wbuf + (size_t)layer * 4096;
    uint4* wlo = whi + 2048;
    int lane = id & 63, st = id >> 6;          // st = s*8 + t
    int s = st >> 3, t = st & 7;
    int col = t * 16 + (lane & 15);
    int kb = s * 32 + ((lane >> 4) & 3) * 8;
    Frag H, L;
#pragma unroll
    for (int j = 0; j < 8; ++j) {
        float x = W[(size_t)(kb + j) * D + col];
        unsigned u = __float_as_uint(x);
        unsigned r = (u + 0x7fffu + ((u >> 16) & 1)) & 0xffff0000u;
        H.s[j] = (unsigned short)(r >> 16);
        L.s[j] = bf16_rne(x - __uint_as_float(r));
    }
    whi[st * 64 + lane] = H.u;
    wlo[st * 64 + lane] = L.u;
}

// ---------------- GEMM: H(bf16) = preop(A) @ W via split-bf16 MFMA ---------
// f32 = bf16_hi + bf16_lo; D = Ah*Wh + Al*Wh + Ah*Wl (dropped Al*Wl <= 2^-18).
// Output h stored as bf16 (agg is its only consumer -> halves gather bytes).
template <int PRE>   // 0: identity, 1: relu on A-load
__global__ __launch_bounds__(256) void gemm_mfma_k(const float* __restrict__ A,
        const uint4* __restrict__ whi, const uint4* __restrict__ wlo,
        unsigned short* __restrict__ H, int M) {
    int wv = threadIdx.x >> 6, lane = threadIdx.x & 63;
    int row0 = blockIdx.x * 64 + wv * 16;
    int arow = row0 + (lane & 15);
    if (arow >= M) arow = M - 1;                       // clamp; stores guarded
    const float* ap = A + (size_t)arow * D + ((lane >> 4) & 3) * 8;
    f32x4 acc[8];
#pragma unroll
    for (int t = 0; t < 8; ++t) acc[t] = (f32x4){0.f, 0.f, 0.f, 0.f};
#pragma unroll
    for (int s = 0; s < 4; ++s) {
        float4 a0 = *(const float4*)(ap + s * 32);
        float4 a1 = *(const float4*)(ap + s * 32 + 4);
        float av[8] = {a0.x, a0.y, a0.z, a0.w, a1.x, a1.y, a1.z, a1.w};
        Frag Ah, Al;
#pragma unroll
        for (int j = 0; j < 8; ++j) {
            float x = av[j];
            if (PRE) x = fmaxf(x, 0.f);
            unsigned u = __float_as_uint(x);
            unsigned r = (u + 0x7fffu + ((u >> 16) & 1)) & 0xffff0000u;
            Ah.s[j] = (unsigned short)(r >> 16);
            Al.s[j] = bf16_rne(x - __uint_as_float(r));
        }
        const uint4* wh = whi + (size_t)s * 8 * 64 + lane;
        const uint4* wl = wlo + (size_t)s * 8 * 64 + lane;
#pragma unroll
        for (int t = 0; t < 8; ++t) {
            Frag Bh, Bl;
            Bh.u = wh[t * 64];
            Bl.u = wl[t * 64];
            acc[t] = __builtin_amdgcn_mfma_f32_16x16x32_bf16(Ah.v, Bh.v, acc[t], 0, 0, 0);
            acc[t] = __builtin_amdgcn_mfma_f32_16x16x32_bf16(Al.v, Bh.v, acc[t], 0, 0, 0);
            acc[t] = __builtin_amdgcn_mfma_f32_16x16x32_bf16(Ah.v, Bl.v, acc[t], 0, 0, 0);
        }
    }
    // C/D layout (m89-verified): col = lane&15, row = (lane>>4)*4 + reg
    int g = (lane >> 4) & 3, c = lane & 15;
#pragma unroll
    for (int r = 0; r < 4; ++r) {
        int row = row0 + g * 4 + r;
        if (row < M) {
#pragma unroll
            for (int t = 0; t < 8; ++t)
                H[(size_t)row * D + t * 16 + c] = bf16_rne(acc[t][r]);
        }
    }
}

// ---------------- CSR aggregation: out[n] = b + dinv[n]^2 h[n] + sum --------
// one wave per node; 64 lanes x (2 bf16 = 1 uint) = 128 cols; 8-edge unroll.
// h is bf16 -> 256 B/row gather (halved demand vs f32). w = dinv[s]*dn
// recomputed (wave-uniform broadcast loads, L2-resident).
__global__ __launch_bounds__(256) void agg_k(const unsigned int* __restrict__ hu,
                                             const float* __restrict__ dinv,
                                             const int* __restrict__ rp,
                                             const int* __restrict__ csr,
                                             const float* __restrict__ bias,
                                             float* __restrict__ out, int n) {
    int node = (blockIdx.x << 2) + (threadIdx.x >> 6);
    int lane = threadIdx.x & 63;
    if (node >= n) return;
    float2 b2 = ((const float2*)bias)[lane];
    float dn = dinv[node];
    unsigned hv = hu[(size_t)node * 64 + lane];
    float sl = dn * dn;   // self-loop norm
    float accx = b2.x + sl * __uint_as_float(hv << 16);
    float accy = b2.y + sl * __uint_as_float(hv & 0xffff0000u);
    int e = rp[node], e1 = rp[node + 1];
    for (; e + 8 <= e1; e += 8) {
        int s0 = csr[e + 0], s1 = csr[e + 1], s2 = csr[e + 2], s3 = csr[e + 3];
        int s4 = csr[e + 4], s5 = csr[e + 5], s6 = csr[e + 6], s7 = csr[e + 7];
        unsigned u0 = hu[(size_t)s0 * 64 + lane];
        unsigned u1 = hu[(size_t)s1 * 64 + lane];
        unsigned u2 = hu[(size_t)s2 * 64 + lane];
        unsigned u3 = hu[(size_t)s3 * 64 + lane];
        unsigned u4 = hu[(size_t)s4 * 64 + lane];
        unsigned u5 = hu[(size_t)s5 * 64 + lane];
        unsigned u6 = hu[(size_t)s6 * 64 + lane];
        unsigned u7 = hu[(size_t)s7 * 64 + lane];
        float w0 = dinv[s0] * dn, w1 = dinv[s1] * dn;
        float w2 = dinv[s2] * dn, w3 = dinv[s3] * dn;
        float w4 = dinv[s4] * dn, w5 = dinv[s5] * dn;
        float w6 = dinv[s6] * dn, w7 = dinv[s7] * dn;
        accx += w0 * __uint_as_float(u0 << 16) + w1 * __uint_as_float(u1 << 16)
              + w2 * __uint_as_float(u2 << 16) + w3 * __uint_as_float(u3 << 16)
              + w4 * __uint_as_float(u4 << 16) + w5 * __uint_as_float(u5 << 16)
              + w6 * __uint_as_float(u6 << 16) + w7 * __uint_as_float(u7 << 16);
        accy += w0 * __uint_as_float(u0 & 0xffff0000u) + w1 * __uint_as_float(u1 & 0xffff0000u)
              + w2 * __uint_as_float(u2 & 0xffff0000u) + w3 * __uint_as_float(u3 & 0xffff0000u)
              + w4 * __uint_as_float(u4 & 0xffff0000u) + w5 * __uint_as_float(u5 & 0xffff0000u)
              + w6 * __uint_as_float(u6 & 0xffff0000u) + w7 * __uint_as_float(u7 & 0xffff0000u);
    }
    for (; e < e1; ++e) {
        int s0 = csr[e];
        float w0 = dinv[s0] * dn;
        unsigned u0 = hu[(size_t)s0 * 64 + lane];
        accx += w0 * __uint_as_float(u0 << 16);
        accy += w0 * __uint_as_float(u0 & 0xffff0000u);
    }
    float2 o; o.x = accx; o.y = accy;
    ((float2*)out)[(size_t)node * 64 + lane] = o;
}

extern "C" void kernel_launch(void* const* d_in, const int* in_sizes, int n_in,
                              void* d_out, int out_size, void* d_ws, size_t ws_size,
                              hipStream_t stream) {
    const float* x  = (const float*)d_in[0];
    const int* eraw = (const int*)d_in[1];
    const float* W1 = (const float*)d_in[2];
    const float* b1 = (const float*)d_in[3];
    const float* W2 = (const float*)d_in[4];
    const float* b2 = (const float*)d_in[5];
    const float* W3 = (const float*)d_in[6];
    const float* b3 = (const float*)d_in[7];
    int N = in_sizes[0] / D;
    int E = in_sizes[1] / 2;
    float* out = (float*)d_out;

    // workspace carve-up (~40 MB)
    char* w = (char*)d_ws;
    unsigned int* h = (unsigned int*)w; w += (size_t)N * D * 2;   // bf16 h
    int* csr    = (int*)w;   w += (size_t)E * 4;
    int* cnt    = (int*)w;   w += (size_t)N * 4;
    float* dinv = (float*)w; w += (size_t)N * 4;
    int* rp     = (int*)w;   w += (size_t)(N + 1) * 4;
    int* cursor = (int*)w;   w += (size_t)N * 4;
    int* part   = (int*)w;   w += 1024 * 4;
    int* flag   = (int*)w;   w += 16;
    uint4* wbuf = (uint4*)w; w += 3 * 4096 * 16;   // [layer][hi 2048 | lo 2048]

    // graph structure (recomputed every call; inputs restored by harness)
    detect64_k<<<1, 256, 0, stream>>>(eraw, flag);
    hipMemsetAsync(cnt, 0, (size_t)N * 4, stream);
    hist_k<<<512, 256, 0, stream>>>(eraw, flag, cnt, E);
    dinv_k<<<(N + 255) / 256, 256, 0, stream>>>(cnt, dinv, N);
    int nb = (N + 1023) / 1024;
    scan1_k<<<nb, 256, 0, stream>>>(cnt, rp, part, N);
    scan2_k<<<1, 256, 0, stream>>>(part, nb);
    scan3_k<<<(N + 255) / 256, 256, 0, stream>>>(rp, cursor, part, N, E);
    build_k<<<512, 256, 0, stream>>>(eraw, flag, cursor, csr, E);

    // W frag pre-pack (hi/lo split, MFMA lane order), all 3 layers
    pack_k<<<24, 256, 0, stream>>>(W1, W2, W3, wbuf);

    int gb = (N + 63) / 64;
    int ab = (N + 3) / 4;
    uint4* whi1 = wbuf, *wlo1 = wbuf + 2048;
    uint4* whi2 = wbuf + 4096, *wlo2 = wbuf + 6144;
    uint4* whi3 = wbuf + 8192, *wlo3 = wbuf + 10240;
    // layer 1
    gemm_mfma_k<0><<<gb, 256, 0, stream>>>(x, whi1, wlo1, (unsigned short*)h, N);
    agg_k<<<ab, 256, 0, stream>>>(h, dinv, rp, csr, b1, out, N);
    // layer 2 (relu fused into A-load)
    gemm_mfma_k<1><<<gb, 256, 0, stream>>>(out, whi2, wlo2, (unsigned short*)h, N);
    agg_k<<<ab, 256, 0, stream>>>(h, dinv, rp, csr, b2, out, N);
    // layer 3 (no relu after)
    gemm_mfma_k<1><<<gb, 256, 0, stream>>>(out, whi3, wlo3, (unsigned short*)h, N);
    agg_k<<<ab, 256, 0, stream>>>(h, dinv, rp, csr, b3, out, N);
}